// Round 5
// baseline (74.358 us; speedup 1.0000x reference)
//
#include <hip/hip_runtime.h>
#include <math.h>

#define NN 256
#define BATCH 64
#define PB 4
#define NB (BATCH + PB)     // 68 slabs (64 real + 4 identity pseudo-slabs)
#define KMAX 8              // moments m_0..m_8 (series tail ~1e-8 in phi)
#define NM (KMAX + 1)
#define NSTEPS (KMAX / 2)   // 4 chain steps
#define CG 2                // column groups per slab
#define CW 32               // columns per group
#define YSTR 264            // LDS k-stride (528B row -> 2-way bank alias = free)
#define NPART 8             // partials per (slab, moment): 2 groups x 4 waves

using short8 = __attribute__((ext_vector_type(8))) short;
using us4    = __attribute__((ext_vector_type(4))) unsigned short;
using f32x4  = __attribute__((ext_vector_type(4))) float;

__device__ __forceinline__ float bf2f(unsigned short u) {
    union { unsigned int i; float f; } v; v.i = ((unsigned int)u) << 16; return v.f;
}
__device__ __forceinline__ unsigned short f2bf(float f) {
    union { float f; unsigned int i; } v; v.f = f;
    unsigned int b = v.i;
    return (unsigned short)((b + 0x7FFFu + ((b >> 16) & 1u)) >> 16);
}

// ---------------------------------------------------------------------------
// jbuild: Jb = bf16(0.5*(Jr+Jr^T), zero diag).
// ---------------------------------------------------------------------------
__global__ void jbuild_kernel(const float* __restrict__ Jr,
                              unsigned short* __restrict__ Jb) {
    int i = blockIdx.x * 256 + threadIdx.x;     // 256 blocks -> 65536
    int r = i >> 8, c = i & 255;
    float v = (r == c) ? 0.0f : 0.5f * (Jr[i] + Jr[(c << 8) + r]);
    Jb[i] = f2bf(v);
}

// ---------------------------------------------------------------------------
// chain: block = (column-group g, slab b), 256 thr, 1 block/CU (136 blocks).
// Wave w owns output rows w*64..w*64+63; its 64x256 slice of J is loaded ONCE
// into 128 VGPRs of A-fragments. y (32 cols) ping-pongs in LDS. 4 steps of
// y <- J*y, each fusing the two fp32 dots m_{2j-1}=<y_{j-1},y_j>,
// m_{2j}=<y_j,y_j>. Per-wave partials plain-stored (no atomics, no global
// drain before the per-step LDS barrier).
// ---------------------------------------------------------------------------
__global__ __launch_bounds__(256, 1)
void chain_kernel(const unsigned short* __restrict__ J,
                  const float* __restrict__ x,
                  float* __restrict__ partial) {
    __shared__ unsigned short ybuf[2][CW][YSTR];
    const int g = blockIdx.x;          // 0..CG-1
    const int b = blockIdx.y;          // 0..67
    const int t = threadIdx.x;
    const int w = t >> 6;
    const int lane = t & 63;
    const int quad = lane >> 4;
    const int l15 = lane & 15;

    // ---- J A-fragments into registers (once) ----
    short8 afr[4][8];
#pragma unroll
    for (int mt = 0; mt < 4; ++mt)
#pragma unroll
        for (int kc = 0; kc < 8; ++kc)
            afr[mt][kc] = *(const short8*)(J + ((w * 64 + mt * 16 + l15) << 8)
                                             + kc * 32 + quad * 8);

    // ---- y0 into ybuf[0]; fused fp32 m0 partial for real slabs ----
    if (b < BATCH) {
        const float* xb = x + (b << 14) + g * CW;    // x[b][k][g*32..]
        float s0 = 0.f;
#pragma unroll
        for (int it = 0; it < 8; ++it) {
            int k = it * 32 + (t >> 3);
            int nn = (t & 7) * 4;
            float4 v = *(const float4*)(xb + (k << 6) + nn);
            s0 += v.x * v.x + v.y * v.y + v.z * v.z + v.w * v.w;
            ybuf[0][nn + 0][k] = f2bf(v.x);
            ybuf[0][nn + 1][k] = f2bf(v.y);
            ybuf[0][nn + 2][k] = f2bf(v.z);
            ybuf[0][nn + 3][k] = f2bf(v.w);
        }
#pragma unroll
        for (int o = 32; o > 0; o >>= 1) s0 += __shfl_down(s0, o);
        if (lane == 0) partial[(b * NM + 0) * NPART + g * 4 + w] = s0;
    } else {
        int p = b - BATCH;
        for (int i = t; i < CW * 256; i += 256) ybuf[0][i >> 8][i & 255] = 0;
        __syncthreads();
        if (t < CW) ybuf[0][t][p * 64 + g * CW + t] = 0x3F80;  // e_{p*64+g*32+t}
    }
    __syncthreads();

    int cur = 0;
    for (int j = 1; j <= NSTEPS; ++j) {
        f32x4 acc[4][2] = {};
#pragma unroll
        for (int kc = 0; kc < 8; ++kc) {
            short8 bfr[2];
#pragma unroll
            for (int nt = 0; nt < 2; ++nt)
                bfr[nt] = *(const short8*)&ybuf[cur][nt * 16 + l15][kc * 32 + quad * 8];
#pragma unroll
            for (int mt = 0; mt < 4; ++mt)
#pragma unroll
                for (int nt = 0; nt < 2; ++nt)
                    acc[mt][nt] = __builtin_amdgcn_mfma_f32_16x16x32_bf16(
                        afr[mt][kc], bfr[nt], acc[mt][nt], 0, 0, 0);
        }

        const int nxt = cur ^ 1;
        float d1 = 0.f, d2 = 0.f;
#pragma unroll
        for (int mt = 0; mt < 4; ++mt) {
            int mbase = w * 64 + mt * 16 + quad * 4;   // rows are k-contiguous
#pragma unroll
            for (int nt = 0; nt < 2; ++nt) {
                int col = nt * 16 + l15;
                us4 prev = *(const us4*)&ybuf[cur][col][mbase];
                us4 outv;
#pragma unroll
                for (int r = 0; r < 4; ++r) {
                    float v = acc[mt][nt][r];
                    d1 += bf2f(prev[r]) * v;
                    d2 += v * v;
                    outv[r] = f2bf(v);
                }
                *(us4*)&ybuf[nxt][col][mbase] = outv;
            }
        }
#pragma unroll
        for (int o = 32; o > 0; o >>= 1) {
            d1 += __shfl_down(d1, o);
            d2 += __shfl_down(d2, o);
        }
        if (lane == 0) {
            partial[(b * NM + 2 * j - 1) * NPART + g * 4 + w] = d1;
            partial[(b * NM + 2 * j    ) * NPART + g * 4 + w] = d2;
        }
        cur = nxt;
        __syncthreads();
    }
}

// ---------------------------------------------------------------------------
// solve: sum the 8 partials per (slab, moment), then per-batch fp32 Newton
// with early exit (== reference's gated update), then phi/afe.
// T_k = sum over 4 pseudo slabs; T_0 = 256 analytic.
// ---------------------------------------------------------------------------
__global__ void solve_kernel(const float* __restrict__ partial, float* __restrict__ out) {
    int b = threadIdx.x;
    if (b >= BATCH) return;
    float mk[NM], Tk[NM];
    Tk[0] = 256.0f;
#pragma unroll
    for (int k = 0; k < NM; ++k) {
        float s = 0.f;
#pragma unroll
        for (int i = 0; i < NPART; ++i) s += partial[(b * NM + k) * NPART + i];
        mk[k] = s;
        if (k >= 1) {
            float tv = 0.f;
            for (int p = 0; p < PB; ++p)
#pragma unroll
                for (int i = 0; i < NPART; ++i)
                    tv += partial[((BATCH + p) * NM + k) * NPART + i];
            Tk[k] = tv;
        }
    }
    float t = 1.0f;
    for (int it = 0; it < 40; ++it) {
        float inv = 1.0f / t;
        float p1 = inv, S1 = 0.f, S1d = 0.f, S3 = 0.f, S3d = 0.f;
#pragma unroll
        for (int k = 0; k < NM; ++k) {
            float p2 = p1 * inv;
            float p3 = p2 * inv;
            float kp1 = (float)(k + 1);
            S1  += Tk[k] * p1;
            S1d += kp1 * Tk[k] * p2;
            S3  += kp1 * mk[k] * p2;
            S3d += kp1 * (float)(k + 2) * mk[k] * p3;
            p1 = p2;
        }
        float f  = 256.0f - 0.5f * S1 - S3 * (1.0f / 256.0f);
        float df = 0.5f * S1d + S3d * (1.0f / 256.0f);
        if (fabsf(f) <= 1e-4f) break;
        t -= f / df;
    }
    float inv = 1.0f / t;
    float logdet = 256.0f * logf(t);
    float quad = 0.f;
    float p1 = inv, pk = 1.0f;
#pragma unroll
    for (int k = 0; k < NM; ++k) {
        quad += mk[k] * p1;
        if (k >= 1) { pk *= inv; logdet -= Tk[k] / (float)k * pk; }
        p1 *= inv;
    }
    float phi = 256.0f * t - 0.5f * logdet + quad * (1.0f / 256.0f);
    float afe = -(0.5f * logf((float)M_PI) + phi * (1.0f / 256.0f));
    out[b] = afe;
    out[BATCH + b] = t;
}

// ---------------------------------------------------------------------------
extern "C" void kernel_launch(void* const* d_in, const int* in_sizes, int n_in,
                              void* d_out, int out_size, void* d_ws, size_t ws_size,
                              hipStream_t stream) {
    const float* x  = (const float*)d_in[0];
    const float* Jr = (const float*)d_in[1];
    float* out = (float*)d_out;

    char* base = (char*)d_ws;
    unsigned short* Jb = (unsigned short*)base;          // 128 KB
    float* partial = (float*)(base + 131072);            // 68*9*8 floats

    jbuild_kernel<<<256, 256, 0, stream>>>(Jr, Jb);
    chain_kernel<<<dim3(CG, NB), 256, 0, stream>>>(Jb, x, partial);
    solve_kernel<<<1, 64, 0, stream>>>(partial, out);
}